// Round 11
// baseline (117.907 us; speedup 1.0000x reference)
//
#include <hip/hip_runtime.h>
#include <stdint.h>

// BinarizeLinear: out[i][j] = sum_k sign(x[i][k]) * sign(W[j][k]) + bias[j]
// R11: co-residency attack. R3/R10 identical perf (83 µs, MfmaUtil 33%) showed
// the limiter is un-hidden per-block tails (prologue fill, epilogue, endpgm
// C-store drain ~10 µs/block) -- 128 KiB LDS forced 1 block/CU so tails
// serialize. New shape: tile 128x256, BK=64, LDS 48 KB, 8 waves of 64x64,
// __launch_bounds__(512,4) caps regs at 128 (acc 64 + a 16 + b 16 + addr ~120)
// -> 2 independent blocks/CU; tails of one hide under the other's main loop.
// Schedule (race-free by construction): LOAD(cur) -> lgkm(0) -> BAR ->
// STAGE(cur,t+2) -> MFMA -> vmcnt(3) -> BAR. Stages touch a buffer only after
// the barrier confirming all reads of it; vmcnt(3) = the 3 fresh t+2 stages,
// so tile t+1 is resident at its first read.
// Swizzle: R1's verified BK=64 involution slot^((row>>1)&3) (0 conflicts),
// applied to BOTH stage-source and ds_read (rule #21).
// Exact: +-1 products, int sums <= 2048 -> fp32-exact vs reference.

#define Mdim 16384
#define Ndim 2048
#define Kdim 2048
#define NT 32  // K-tiles of 64 i8 elements

using i32x4 = __attribute__((ext_vector_type(4))) int;

__global__ __launch_bounds__(256) void binarize_both(const float* __restrict__ x,
                                                     const float* __restrict__ w,
                                                     int8_t* __restrict__ out,
                                                     int nx16, int ntot16) {
  int i = blockIdx.x * 256 + threadIdx.x;
  if (i >= ntot16) return;
  const float4* p = (i < nx16) ? ((const float4*)x + (size_t)i * 4)
                               : ((const float4*)w + (size_t)(i - nx16) * 4);
  float4 f0 = p[0], f1 = p[1], f2 = p[2], f3 = p[3];
  float s[16] = {f0.x, f0.y, f0.z, f0.w, f1.x, f1.y, f1.z, f1.w,
                 f2.x, f2.y, f2.z, f2.w, f3.x, f3.y, f3.z, f3.w};
  union { int8_t b[16]; int4 v; } u;
#pragma unroll
  for (int j = 0; j < 16; ++j) u.b[j] = s[j] > 0.0f ? (int8_t)1 : (int8_t)-1;
  ((int4*)out)[i] = u.v;  // xb then wb, contiguous
}

__device__ __forceinline__ void gl_lds16(const void* gsrc, void* ldst) {
  __builtin_amdgcn_global_load_lds(
      (const __attribute__((address_space(1))) void*)gsrc,
      (__attribute__((address_space(3))) void*)ldst, 16, 0, 0);
}

__global__ __launch_bounds__(512, 4) void bin_gemm_i8_co(const int8_t* __restrict__ A,
                                                         const int8_t* __restrict__ W,
                                                         const float* __restrict__ bias,
                                                         float* __restrict__ C) {
  // A: [2][128 rows][64 B] = 16 KB; B: [2][256 rows][64 B] = 32 KB. 48 KB total.
  __shared__ __align__(16) int8_t As[2][128 * 64];
  __shared__ __align__(16) int8_t Bs[2][256 * 64];

  const int tid = threadIdx.x;
  const int lane = tid & 63;
  const int wid = tid >> 6;  // 0..7
  const int wm = wid >> 2;   // 0..1 (M half: 64 rows)
  const int wn = wid & 3;    // 0..3 (N quarter: 64 cols)

  // XCD swizzle: 1024 blocks, %8==0 -> bijective. Per XCD: 16 consecutive
  // M-panels x all 8 col-tiles -> A-panel re-reads are L2-local; wb (4 MB)
  // fully L2-resident per XCD.
  const int bid = blockIdx.x;
  const int swz = (bid & 7) * 128 + (bid >> 3);
  const long brow = (long)(swz >> 3) * 128;  // 128 M-tiles
  const long bcol = (long)(swz & 7) * 256;   // 8 col-tiles

  // ---- staging: linear LDS dest; swizzle on global SOURCE slot.
  // Rows per gl_lds inst: 16 (4 lanes x 16 B per 64 B row).
  // f(row) = (row>>1)&3; row = (16|32-mult) + lane>>2 -> f = (lane>>3)&3.
  const int slin = lane & 3;
  const int sgcol = (slin ^ ((lane >> 3) & 3)) * 16;
  const int srA = wid * 16 + (lane >> 2);   // A rows (1 inst/wave)
  const int srB = wid * 32 + (lane >> 2);   // B rows (2 insts/wave: +0, +16)

  // ---- fragment ds_read byte offsets (swizzled: slot ^ ((row>>1)&3)) ----
  int offA[4], offB[4];
#pragma unroll
  for (int fr = 0; fr < 4; ++fr) {
    const int ra = wm * 64 + fr * 16 + (lane & 15);
    const int s = lane >> 4;
    offA[fr] = ra * 64 + ((s ^ ((ra >> 1) & 3)) * 16);
  }
#pragma unroll
  for (int fc = 0; fc < 4; ++fc) {
    const int rb = wn * 64 + fc * 16 + (lane & 15);
    const int s = lane >> 4;
    offB[fc] = rb * 64 + ((s ^ ((rb >> 1) & 3)) * 16);
  }

  i32x4 acc[4][4] = {};  // 64 regs
  i32x4 a[4], b[4];      // 16 + 16 regs

#define BAR() asm volatile("s_barrier" ::: "memory")
#define STAGE(BUF, KT)                                                              \
  do {                                                                              \
    const int8_t* sa_ = A + (brow + srA) * (long)Kdim + ((long)(KT) << 6) + sgcol;  \
    gl_lds16(sa_, &As[BUF][wid * 1024]);                                            \
    const int8_t* sb_ = W + (bcol + srB) * (long)Kdim + ((long)(KT) << 6) + sgcol;  \
    gl_lds16(sb_, &Bs[BUF][wid * 2048]);                                            \
    gl_lds16(sb_ + (long)16 * Kdim, &Bs[BUF][wid * 2048 + 1024]);                   \
  } while (0)

  // ---- prologue: stage tiles 0,1 (3 gl_lds/wave each); tile0 resident.
  STAGE(0, 0);
  STAGE(1, 1);
  asm volatile("s_waitcnt vmcnt(3)" ::: "memory");
  BAR();

#pragma unroll 1
  for (int t = 0; t < NT; ++t) {
    const int cur = t & 1;

    // reads of buf cur (8 x ds_read_b128), drained before the barrier
#pragma unroll
    for (int fr = 0; fr < 4; ++fr) a[fr] = *(const i32x4*)&As[cur][offA[fr]];
#pragma unroll
    for (int fc = 0; fc < 4; ++fc) b[fc] = *(const i32x4*)&Bs[cur][offB[fc]];
    asm volatile("s_waitcnt lgkmcnt(0)" ::: "memory");
    BAR();  // all waves done reading buf cur

    // overwrite cur with tile t+2 (safe: post-barrier)
    if (t + 2 < NT) STAGE(cur, t + 2);

    __builtin_amdgcn_s_setprio(1);
#pragma unroll
    for (int fr = 0; fr < 4; ++fr)
#pragma unroll
      for (int fc = 0; fc < 4; ++fc)
        acc[fr][fc] = __builtin_amdgcn_mfma_i32_16x16x64_i8(a[fr], b[fc], acc[fr][fc], 0, 0, 0);
    __builtin_amdgcn_s_setprio(0);

    // retire tile t+1's stages (3 newest = tile t+2's, just issued)
    if (t < NT - 2) {
      asm volatile("s_waitcnt vmcnt(3)" ::: "memory");
    } else {
      asm volatile("s_waitcnt vmcnt(0)" ::: "memory");
    }
    BAR();
  }

  // ---- epilogue: C/D layout col=lane&15, row=(lane>>4)*4+reg ----
#pragma unroll
  for (int fc = 0; fc < 4; ++fc) {
    const long col = bcol + wn * 64 + fc * 16 + (lane & 15);
    const float bj = bias[col];
#pragma unroll
    for (int fr = 0; fr < 4; ++fr) {
      const long row0 = brow + wm * 64 + fr * 16 + (lane >> 4) * 4;
#pragma unroll
      for (int r = 0; r < 4; ++r) {
        C[(row0 + r) * (long)Ndim + col] = (float)acc[fr][fc][r] + bj;
      }
    }
  }
#undef BAR
#undef STAGE
}

extern "C" void kernel_launch(void* const* d_in, const int* in_sizes, int n_in,
                              void* d_out, int out_size, void* d_ws, size_t ws_size,
                              hipStream_t stream) {
  const float* x = (const float*)d_in[0];
  const float* w = (const float*)d_in[1];
  const float* bias = (const float*)d_in[2];
  float* out = (float*)d_out;

  int8_t* xb = (int8_t*)d_ws;             // 33.5 MB
  int8_t* wb = xb + (size_t)Mdim * Kdim;  // + 4.2 MB (ws >= 37.8 MB)

  const int nx16 = Mdim * Kdim / 16;
  const int nw16 = Ndim * Kdim / 16;
  const int ntot16 = nx16 + nw16;
  binarize_both<<<(ntot16 + 255) / 256, 256, 0, stream>>>(x, w, xb, nx16, ntot16);

  dim3 grid((Mdim / 128) * (Ndim / 256));  // 1024 blocks, %8==0
  bin_gemm_i8_co<<<grid, 512, 0, stream>>>(xb, wb, bias, out);
}